// Round 1
// baseline (123.822 us; speedup 1.0000x reference)
//
#include <hip/hip_runtime.h>
#include <math.h>

#define BB  4
#define KK  16
#define MSn 4096
#define NTn 16384

// Kernel 1: val[b,m] = sigmoid(conv_b + sum_k w[k] * softmax_k(logits[b,:,m]))
__global__ __launch_bounds__(256) void sgg_val_kernel(
    const float* __restrict__ logits,  // [B,K,MS]
    const float* __restrict__ w,       // [1,K,1] -> w[k]
    const float* __restrict__ bias,    // [1]
    float* __restrict__ val)           // [B,MS]
{
    int i = blockIdx.x * 256 + threadIdx.x;   // i in [0, B*MS)
    int b = i >> 12;                          // / 4096
    int m = i & 4095;
    const float* base = logits + (size_t)b * KK * MSn + m;

    float x[KK];
    float mx = -INFINITY;
#pragma unroll
    for (int k = 0; k < KK; ++k) {
        x[k] = base[(size_t)k * MSn];         // coalesced across m
        mx = fmaxf(mx, x[k]);
    }
    float sum = 0.f;
#pragma unroll
    for (int k = 0; k < KK; ++k) {
        x[k] = expf(x[k] - mx);
        sum += x[k];
    }
    float inv = 1.0f / sum;
    float acc = bias[0];
#pragma unroll
    for (int k = 0; k < KK; ++k) {
        acc += w[k] * (x[k] * inv);
    }
    val[i] = 1.0f / (1.0f + expf(-acc));
}

// Kernel 2: per target, argmin_m d2(t,s_m) with reference-exact arithmetic,
// then out[b,n] = val[b, argmin].
// d2 = (tt - 2*dot) + ss, all ops IEEE f32, no FMA contraction, left-assoc sums.
__global__ __launch_bounds__(256) void sgg_nn_kernel(
    const float* __restrict__ spos,    // [B,3,MS]
    const float* __restrict__ tpos,    // [B,3,NT]
    const float* __restrict__ val,     // [B,MS]
    float* __restrict__ out)           // [B,NT]
{
    __shared__ float4 s[MSn];          // 64 KB: (s0,s1,s2,ss) per source

    int b     = blockIdx.x >> 6;       // 64 chunks of 256 targets per batch
    int chunk = blockIdx.x & 63;

    const float* sp = spos + (size_t)b * 3 * MSn;
    for (int j = threadIdx.x; j < MSn; j += 256) {
        float s0 = sp[j];
        float s1 = sp[MSn + j];
        float s2 = sp[2 * MSn + j];
        float ss = __fadd_rn(__fadd_rn(__fmul_rn(s0, s0), __fmul_rn(s1, s1)),
                             __fmul_rn(s2, s2));
        s[j] = make_float4(s0, s1, s2, ss);
    }
    __syncthreads();

    int n = chunk * 256 + threadIdx.x;
    const float* tp = tpos + (size_t)b * 3 * NTn;
    float t0 = tp[n];
    float t1 = tp[NTn + n];
    float t2 = tp[2 * NTn + n];
    float tt = __fadd_rn(__fadd_rn(__fmul_rn(t0, t0), __fmul_rn(t1, t1)),
                         __fmul_rn(t2, t2));

    float dmin = INFINITY;
    int   imin = 0;
#pragma unroll 8
    for (int m = 0; m < MSn; ++m) {
        float4 sv = s[m];              // wave-uniform address -> LDS broadcast
        float dot = __fadd_rn(__fadd_rn(__fmul_rn(t0, sv.x), __fmul_rn(t1, sv.y)),
                              __fmul_rn(t2, sv.z));
        float d2 = __fadd_rn(__fsub_rn(tt, __fadd_rn(dot, dot)), sv.w);
        bool lt = d2 < dmin;           // strict <: first-occurrence tie-break
        dmin = lt ? d2 : dmin;
        imin = lt ? m  : imin;
    }

    out[(size_t)b * NTn + n] = val[b * MSn + imin];
}

extern "C" void kernel_launch(void* const* d_in, const int* in_sizes, int n_in,
                              void* d_out, int out_size, void* d_ws, size_t ws_size,
                              hipStream_t stream) {
    const float* sem  = (const float*)d_in[0];  // [4,16,4096]
    const float* spos = (const float*)d_in[1];  // [4,3,4096]
    const float* tpos = (const float*)d_in[2];  // [4,3,16384]
    const float* w    = (const float*)d_in[3];  // [1,16,1]
    const float* bias = (const float*)d_in[4];  // [1]
    float* out = (float*)d_out;                 // [4,1,16384]
    float* val = (float*)d_ws;                  // [4,4096] scratch

    sgg_val_kernel<<<(BB * MSn) / 256, 256, 0, stream>>>(sem, w, bias, val);
    sgg_nn_kernel<<<(BB * NTn) / 256, 256, 0, stream>>>(spos, tpos, val, out);
}

// Round 2
// 78.928 us; speedup vs baseline: 1.5688x; 1.5688x over previous
//
#include <hip/hip_runtime.h>
#include <math.h>

#define BB  4
#define KK  16
#define MSn 4096
#define NTn 16384
#define NCHUNK 4
#define CHUNK (MSn / NCHUNK)     // 1024 sources per block
#define TGT_PER_BLK 512          // 256 threads x 2 targets

typedef float f2 __attribute__((ext_vector_type(2)));

// Kernel 1: val[b,m] = sigmoid(conv_b + sum_k w[k] * softmax_k(logits[b,:,m]))
__global__ __launch_bounds__(256) void sgg_val_kernel(
    const float* __restrict__ logits,  // [B,K,MS]
    const float* __restrict__ w,       // [1,K,1]
    const float* __restrict__ bias,    // [1]
    float* __restrict__ val)           // [B,MS]
{
    int i = blockIdx.x * 256 + threadIdx.x;   // [0, B*MS)
    int b = i >> 12;
    int m = i & (MSn - 1);
    const float* base = logits + (size_t)b * KK * MSn + m;

    float x[KK];
    float mx = -INFINITY;
#pragma unroll
    for (int k = 0; k < KK; ++k) {
        x[k] = base[(size_t)k * MSn];
        mx = fmaxf(mx, x[k]);
    }
    float sum = 0.f;
#pragma unroll
    for (int k = 0; k < KK; ++k) {
        x[k] = expf(x[k] - mx);
        sum += x[k];
    }
    float inv = 1.0f / sum;
    float acc = bias[0];
#pragma unroll
    for (int k = 0; k < KK; ++k) {
        acc += w[k] * (x[k] * inv);
    }
    val[i] = 1.0f / (1.0f + expf(-acc));
}

// Kernel 2: partial NN scan over a 1024-source chunk, 2 targets/thread.
// Exact reference arithmetic: d2 = (tt - (dot+dot)) + ss, left-assoc sums,
// no FMA contraction (pragma). Merge across chunks via atomicMin on
// packed (monotone-float-key<<32 | global_m): equal d2 -> smaller m wins,
// which reproduces jnp.argmin first-occurrence semantics exactly.
__global__ __launch_bounds__(256) void sgg_nn_kernel(
    const float* __restrict__ spos,    // [B,3,MS]
    const float* __restrict__ tpos,    // [B,3,NT]
    unsigned long long* __restrict__ keys)  // [B*NT]
{
    __shared__ float4 s[CHUNK];        // 16 KB

    int tg    = blockIdx.x >> 2;       // 128 target groups of 512 targets
    int chunk = blockIdx.x & (NCHUNK - 1);
    int b     = tg >> 5;               // 32 target groups per batch
    int cbase = chunk * CHUNK;

    const float* sp = spos + (size_t)b * 3 * MSn + cbase;
    for (int j = threadIdx.x; j < CHUNK; j += 256) {
        float s0 = sp[j];
        float s1 = sp[MSn + j];
        float s2 = sp[2 * MSn + j];
        float ss = __fadd_rn(__fadd_rn(__fmul_rn(s0, s0), __fmul_rn(s1, s1)),
                             __fmul_rn(s2, s2));
        s[j] = make_float4(s0, s1, s2, ss);
    }
    __syncthreads();

    int nA = tg * TGT_PER_BLK + threadIdx.x;   // global target id
    int nB = nA + 256;
    int lA = nA & (NTn - 1);                   // within-batch target id
    int lB = nB & (NTn - 1);
    const float* tp = tpos + (size_t)b * 3 * NTn;

    f2 t0 = { tp[lA],           tp[lB] };
    f2 t1 = { tp[NTn + lA],     tp[NTn + lB] };
    f2 t2 = { tp[2 * NTn + lA], tp[2 * NTn + lB] };
    f2 tt;
    {
#pragma clang fp contract(off)
        tt = ((t0 * t0) + (t1 * t1)) + (t2 * t2);
    }

    float dminA = INFINITY, dminB = INFINITY;
    int   iminA = 0,        iminB = 0;
#pragma unroll 8
    for (int m = 0; m < CHUNK; ++m) {
        float4 sv = s[m];              // wave-uniform -> LDS broadcast
        f2 d2;
        {
#pragma clang fp contract(off)
            f2 dot = ((t0 * sv.x) + (t1 * sv.y)) + (t2 * sv.z);
            d2 = (tt - (dot + dot)) + sv.w;
        }
        bool ltA = d2.x < dminA;       // strict <: first occurrence wins
        dminA = ltA ? d2.x : dminA;
        iminA = ltA ? m    : iminA;
        bool ltB = d2.y < dminB;
        dminB = ltB ? d2.y : dminB;
        iminB = ltB ? m    : iminB;
    }

    // monotone float->uint key (handles possible tiny negative d2 from rounding)
    unsigned int uA = __float_as_uint(dminA);
    unsigned int kA = (uA & 0x80000000u) ? ~uA : (uA | 0x80000000u);
    unsigned int uB = __float_as_uint(dminB);
    unsigned int kB = (uB & 0x80000000u) ? ~uB : (uB | 0x80000000u);
    unsigned long long pA = ((unsigned long long)kA << 32) | (unsigned int)(cbase + iminA);
    unsigned long long pB = ((unsigned long long)kB << 32) | (unsigned int)(cbase + iminB);
    atomicMin(&keys[nA], pA);
    atomicMin(&keys[nB], pB);
}

// Kernel 3: out[b,n] = val[b, argmin_m]
__global__ __launch_bounds__(256) void sgg_out_kernel(
    const unsigned long long* __restrict__ keys,
    const float* __restrict__ val,
    float* __restrict__ out)
{
    int n = blockIdx.x * 256 + threadIdx.x;    // [0, B*NT)
    int b = n >> 14;
    unsigned int m = (unsigned int)keys[n];    // low 32 bits = global m
    out[n] = val[b * MSn + m];
}

extern "C" void kernel_launch(void* const* d_in, const int* in_sizes, int n_in,
                              void* d_out, int out_size, void* d_ws, size_t ws_size,
                              hipStream_t stream) {
    const float* sem  = (const float*)d_in[0];  // [4,16,4096]
    const float* spos = (const float*)d_in[1];  // [4,3,4096]
    const float* tpos = (const float*)d_in[2];  // [4,3,16384]
    const float* w    = (const float*)d_in[3];  // [1,16,1]
    const float* bias = (const float*)d_in[4];  // [1]
    float* out = (float*)d_out;                 // [4,1,16384]

    unsigned long long* keys = (unsigned long long*)d_ws;          // 512 KB
    float* val = (float*)((char*)d_ws + (size_t)BB * NTn * 8);     // 64 KB

    hipMemsetAsync(d_ws, 0xFF, (size_t)BB * NTn * 8, stream);      // keys = u64 max
    sgg_val_kernel<<<(BB * MSn) / 256, 256, 0, stream>>>(sem, w, bias, val);
    sgg_nn_kernel<<<(BB * NTn / TGT_PER_BLK) * NCHUNK, 256, 0, stream>>>(spos, tpos, keys);
    sgg_out_kernel<<<(BB * NTn) / 256, 256, 0, stream>>>(keys, val, out);
}

// Round 3
// 69.561 us; speedup vs baseline: 1.7800x; 1.1346x over previous
//
#include <hip/hip_runtime.h>
#include <math.h>

#define BB  4
#define KK  16
#define MSn 4096
#define NTn 16384
#define NCHUNK 16
#define CHUNK (MSn / NCHUNK)     // 256 sources per block
#define TT_   4                  // targets per thread
#define TGT_PER_BLK (256 * TT_)  // 1024 targets per block

// Kernel 1: val[b,m] = sigmoid(conv_b + sum_k w[k] * softmax_k(logits[b,:,m]))
__global__ __launch_bounds__(256) void sgg_val_kernel(
    const float* __restrict__ logits,  // [B,K,MS]
    const float* __restrict__ w,       // [1,K,1]
    const float* __restrict__ bias,    // [1]
    float* __restrict__ val)           // [B,MS]
{
    int i = blockIdx.x * 256 + threadIdx.x;   // [0, B*MS)
    int b = i >> 12;
    int m = i & (MSn - 1);
    const float* base = logits + (size_t)b * KK * MSn + m;

    float x[KK];
    float mx = -INFINITY;
#pragma unroll
    for (int k = 0; k < KK; ++k) {
        x[k] = base[(size_t)k * MSn];
        mx = fmaxf(mx, x[k]);
    }
    float sum = 0.f;
#pragma unroll
    for (int k = 0; k < KK; ++k) {
        x[k] = expf(x[k] - mx);
        sum += x[k];
    }
    float inv = 1.0f / sum;
    float acc = bias[0];
#pragma unroll
    for (int k = 0; k < KK; ++k) {
        acc += w[k] * (x[k] * inv);
    }
    val[i] = 1.0f / (1.0f + expf(-acc));
}

// Kernel 2: partial NN scan over a 256-source chunk, 4 targets/thread.
// Reference-exact arithmetic per candidate (7 flops):
//   dot = (t0*s0 + t1*s1) + t2*s2            (muls/adds, no contraction)
//   d2  = fma(-2, dot, tt) + ss              (== (tt - (dot+dot)) + ss exactly,
//                                             since 2*dot is exactly representable)
// Argmin: strict < (first occurrence), merged across chunks via atomicMin on
// packed (monotone-float-key<<32 | global_m) -> equal d2 picks smaller m.
__global__ __launch_bounds__(256, 4) void sgg_nn_kernel(
    const float* __restrict__ spos,    // [B,3,MS]
    const float* __restrict__ tpos,    // [B,3,NT]
    unsigned long long* __restrict__ keys)  // [B*NT]
{
    __shared__ float4 s[CHUNK];        // 4 KB

    int tg    = blockIdx.x >> 4;       // 64 target groups of 1024 targets
    int chunk = blockIdx.x & (NCHUNK - 1);
    int b     = tg >> 4;               // 16 target groups per batch
    int cbase = chunk * CHUNK;

    const float* sp = spos + (size_t)b * 3 * MSn + cbase;
    {
        int j = threadIdx.x;           // 256 threads, 256 sources: 1 each
        float s0 = sp[j];
        float s1 = sp[MSn + j];
        float s2 = sp[2 * MSn + j];
        float ss = __fadd_rn(__fadd_rn(__fmul_rn(s0, s0), __fmul_rn(s1, s1)),
                             __fmul_rn(s2, s2));
        s[j] = make_float4(s0, s1, s2, ss);
    }
    __syncthreads();

    const float* tp = tpos + (size_t)b * 3 * NTn;
    float T0[TT_], T1[TT_], T2[TT_], Q[TT_], DMIN[TT_];
    int   IMIN[TT_], NID[TT_];
#pragma unroll
    for (int j = 0; j < TT_; ++j) {
        int n = (tg & 15) * TGT_PER_BLK + j * 256 + threadIdx.x;  // within-batch
        NID[j] = n;
        T0[j] = tp[n];
        T1[j] = tp[NTn + n];
        T2[j] = tp[2 * NTn + n];
        Q[j]  = __fadd_rn(__fadd_rn(__fmul_rn(T0[j], T0[j]), __fmul_rn(T1[j], T1[j])),
                          __fmul_rn(T2[j], T2[j]));
        DMIN[j] = INFINITY;
        IMIN[j] = 0;
    }

#pragma unroll 8
    for (int m = 0; m < CHUNK; ++m) {
        float4 sv = s[m];              // wave-uniform -> LDS broadcast
#pragma unroll
        for (int j = 0; j < TT_; ++j) {
            float dot = __fadd_rn(__fadd_rn(__fmul_rn(T0[j], sv.x),
                                            __fmul_rn(T1[j], sv.y)),
                                  __fmul_rn(T2[j], sv.z));
            float d2  = __fadd_rn(__builtin_fmaf(-2.0f, dot, Q[j]), sv.w);
            bool  lt  = d2 < DMIN[j];            // strict <: first occurrence
            IMIN[j] = lt ? m : IMIN[j];
            DMIN[j] = __builtin_fminf(DMIN[j], d2);
        }
    }

#pragma unroll
    for (int j = 0; j < TT_; ++j) {
        unsigned int u = __float_as_uint(DMIN[j]);
        unsigned int k = (u & 0x80000000u) ? ~u : (u | 0x80000000u);
        unsigned long long p =
            ((unsigned long long)k << 32) | (unsigned int)(cbase + IMIN[j]);
        atomicMin(&keys[(size_t)b * NTn + NID[j]], p);
    }
}

// Kernel 3: out[b,n] = val[b, argmin_m]
__global__ __launch_bounds__(256) void sgg_out_kernel(
    const unsigned long long* __restrict__ keys,
    const float* __restrict__ val,
    float* __restrict__ out)
{
    int n = blockIdx.x * 256 + threadIdx.x;    // [0, B*NT)
    int b = n >> 14;
    unsigned int m = (unsigned int)keys[n];    // low 32 bits = global m
    out[n] = val[b * MSn + m];
}

extern "C" void kernel_launch(void* const* d_in, const int* in_sizes, int n_in,
                              void* d_out, int out_size, void* d_ws, size_t ws_size,
                              hipStream_t stream) {
    const float* sem  = (const float*)d_in[0];  // [4,16,4096]
    const float* spos = (const float*)d_in[1];  // [4,3,4096]
    const float* tpos = (const float*)d_in[2];  // [4,3,16384]
    const float* w    = (const float*)d_in[3];  // [1,16,1]
    const float* bias = (const float*)d_in[4];  // [1]
    float* out = (float*)d_out;                 // [4,1,16384]

    unsigned long long* keys = (unsigned long long*)d_ws;          // 512 KB
    float* val = (float*)((char*)d_ws + (size_t)BB * NTn * 8);     // 64 KB

    hipMemsetAsync(d_ws, 0xFF, (size_t)BB * NTn * 8, stream);      // keys = u64 max
    sgg_val_kernel<<<(BB * MSn) / 256, 256, 0, stream>>>(sem, w, bias, val);
    sgg_nn_kernel<<<(BB * NTn / TGT_PER_BLK) * NCHUNK, 256, 0, stream>>>(spos, tpos, keys);
    sgg_out_kernel<<<(BB * NTn) / 256, 256, 0, stream>>>(keys, val, out);
}

// Round 4
// 65.638 us; speedup vs baseline: 1.8864x; 1.0598x over previous
//
#include <hip/hip_runtime.h>
#include <math.h>

#define BB  4
#define KK  16
#define MSn 4096
#define NTn 16384
#define NCHUNK 32
#define CHUNK (MSn / NCHUNK)     // 128 sources per block
#define TT_   4                  // targets per thread
#define TGT_PER_BLK (256 * TT_)  // 1024 targets per block

// Kernel 1: val[b,m] = sigmoid(conv_b + sum_k w[k] * softmax_k(logits[b,:,m]))
// Also packs (s0,s1,s2,ss) per source into spack for the NN kernel's
// wave-uniform (scalar-promotable) loads.
__global__ __launch_bounds__(256) void sgg_val_kernel(
    const float* __restrict__ logits,  // [B,K,MS]
    const float* __restrict__ spos,    // [B,3,MS]
    const float* __restrict__ w,       // [1,K,1]
    const float* __restrict__ bias,    // [1]
    float* __restrict__ val,           // [B,MS]
    float4* __restrict__ spack)        // [B,MS]
{
    int i = blockIdx.x * 256 + threadIdx.x;   // [0, B*MS)
    int b = i >> 12;
    int m = i & (MSn - 1);
    const float* base = logits + (size_t)b * KK * MSn + m;

    float x[KK];
    float mx = -INFINITY;
#pragma unroll
    for (int k = 0; k < KK; ++k) {
        x[k] = base[(size_t)k * MSn];
        mx = fmaxf(mx, x[k]);
    }
    float sum = 0.f;
#pragma unroll
    for (int k = 0; k < KK; ++k) {
        x[k] = expf(x[k] - mx);
        sum += x[k];
    }
    float inv = 1.0f / sum;
    float acc = bias[0];
#pragma unroll
    for (int k = 0; k < KK; ++k) {
        acc += w[k] * (x[k] * inv);
    }
    val[i] = 1.0f / (1.0f + expf(-acc));

    // pack source + its exact squared norm (same rounding as reference)
    const float* sp = spos + (size_t)b * 3 * MSn;
    float s0 = sp[m];
    float s1 = sp[MSn + m];
    float s2 = sp[2 * MSn + m];
    float ss = __fadd_rn(__fadd_rn(__fmul_rn(s0, s0), __fmul_rn(s1, s1)),
                         __fmul_rn(s2, s2));
    spack[i] = make_float4(s0, s1, s2, ss);
}

// Kernel 2: partial NN scan over a 128-source chunk, 4 targets/thread.
// Source reads are wave-uniform (loop-counter indexed, read-only restrict)
// -> compiler promotes to s_load; source components ride in SGPRs and the
// inner loop is pure VALU (~10 inst/candidate), no LDS at all.
// Reference-exact d2: dot = (t0*s0 + t1*s1) + t2*s2 ;
// d2 = fma(-2,dot,tt) + ss  (bit-identical to (tt-(dot+dot))+ss since
// 2*dot is exactly representable). Strict < keeps first occurrence.
// Cross-chunk merge: atomicMin on packed (monotone-key<<32 | global_m),
// so equal d2 resolves to the smaller global index -> jnp.argmin semantics.
__global__ __launch_bounds__(256, 8) void sgg_nn_kernel(
    const float4* __restrict__ spack,  // [B,MS] (s0,s1,s2,ss)
    const float* __restrict__ tpos,    // [B,3,NT]
    unsigned long long* __restrict__ keys)  // [B*NT]
{
    int tg    = blockIdx.x >> 5;       // 64 target groups of 1024 targets
    int chunk = blockIdx.x & (NCHUNK - 1);
    int b     = tg >> 4;               // 16 target groups per batch
    int cbase = chunk * CHUNK;
    const float4* sq = spack + (size_t)b * MSn + cbase;

    const float* tp = tpos + (size_t)b * 3 * NTn;
    float T0[TT_], T1[TT_], T2[TT_], Q[TT_], DMIN[TT_];
    int   IMIN[TT_];
    int n0 = (tg & 15) * TGT_PER_BLK + threadIdx.x;   // within-batch target id
#pragma unroll
    for (int j = 0; j < TT_; ++j) {
        int n = n0 + j * 256;
        T0[j] = tp[n];
        T1[j] = tp[NTn + n];
        T2[j] = tp[2 * NTn + n];
        Q[j]  = __fadd_rn(__fadd_rn(__fmul_rn(T0[j], T0[j]), __fmul_rn(T1[j], T1[j])),
                          __fmul_rn(T2[j], T2[j]));
        DMIN[j] = INFINITY;
        IMIN[j] = 0;
    }

#pragma unroll 4
    for (int m = 0; m < CHUNK; ++m) {
        float4 sv = sq[m];             // uniform address -> s_load (SGPRs)
#pragma unroll
        for (int j = 0; j < TT_; ++j) {
            float dot = __fadd_rn(__fadd_rn(__fmul_rn(T0[j], sv.x),
                                            __fmul_rn(T1[j], sv.y)),
                                  __fmul_rn(T2[j], sv.z));
            float d2  = __fadd_rn(__builtin_fmaf(-2.0f, dot, Q[j]), sv.w);
            bool  lt  = d2 < DMIN[j];            // strict <: first occurrence
            IMIN[j] = lt ? m : IMIN[j];
            DMIN[j] = __builtin_fminf(DMIN[j], d2);
        }
    }

#pragma unroll
    for (int j = 0; j < TT_; ++j) {
        unsigned int u = __float_as_uint(DMIN[j]);
        unsigned int k = (u & 0x80000000u) ? ~u : (u | 0x80000000u);
        unsigned long long p =
            ((unsigned long long)k << 32) | (unsigned int)(cbase + IMIN[j]);
        atomicMin(&keys[(size_t)b * NTn + n0 + j * 256], p);
    }
}

// Kernel 3: out[b,n] = val[b, argmin_m]
__global__ __launch_bounds__(256) void sgg_out_kernel(
    const unsigned long long* __restrict__ keys,
    const float* __restrict__ val,
    float* __restrict__ out)
{
    int n = blockIdx.x * 256 + threadIdx.x;    // [0, B*NT)
    int b = n >> 14;
    unsigned int m = (unsigned int)keys[n];    // low 32 bits = global m
    out[n] = val[b * MSn + m];
}

extern "C" void kernel_launch(void* const* d_in, const int* in_sizes, int n_in,
                              void* d_out, int out_size, void* d_ws, size_t ws_size,
                              hipStream_t stream) {
    const float* sem  = (const float*)d_in[0];  // [4,16,4096]
    const float* spos = (const float*)d_in[1];  // [4,3,4096]
    const float* tpos = (const float*)d_in[2];  // [4,3,16384]
    const float* w    = (const float*)d_in[3];  // [1,16,1]
    const float* bias = (const float*)d_in[4];  // [1]
    float* out = (float*)d_out;                 // [4,1,16384]

    unsigned long long* keys = (unsigned long long*)d_ws;              // 512 KB
    float*  val   = (float*)((char*)d_ws + (size_t)BB * NTn * 8);      // 64 KB
    float4* spack = (float4*)((char*)d_ws + (size_t)BB * NTn * 8
                                          + (size_t)BB * MSn * 4);     // 256 KB

    hipMemsetAsync(d_ws, 0xFF, (size_t)BB * NTn * 8, stream);          // keys = max
    sgg_val_kernel<<<(BB * MSn) / 256, 256, 0, stream>>>(sem, spos, w, bias, val, spack);
    sgg_nn_kernel<<<(BB * NTn / TGT_PER_BLK) * NCHUNK, 256, 0, stream>>>(spack, tpos, keys);
    sgg_out_kernel<<<(BB * NTn) / 256, 256, 0, stream>>>(keys, val, out);
}